// Round 3
// baseline (3188.817 us; speedup 1.0000x reference)
//
#include <hip/hip_runtime.h>

typedef unsigned int u32;
typedef unsigned short u16;
typedef short bf16x8 __attribute__((ext_vector_type(8)));
typedef float f32x4 __attribute__((ext_vector_type(4)));

#define S1 12544      // 112*112
#define NSTAT 200704  // 16*112*112
#define EPS 1e-5f
#define AP 264        // padded A-tile row length in bf16 elems (256 + 8)

__device__ __forceinline__ u16 f2bf(float f) {
  union { float f; u32 u; } x; x.f = f;
  u32 r = x.u + 0x7fffu + ((x.u >> 16) & 1u);
  return (u16)(r >> 16);
}
__device__ __forceinline__ void bf2x2(u32 u, float& lo, float& hi) {
  union { u32 u; float f; } a, b;
  a.u = u << 16; b.u = u & 0xffff0000u;
  lo = a.f; hi = b.f;
}

// ---------------- conv1 (3->256, 3x3, stride2, pad1) + bn1 stats ----------------
#define CW 225
__global__ __launch_bounds__(256) void k_conv1(const float* __restrict__ img,
    const float* __restrict__ w, u16* __restrict__ out, float* __restrict__ stats) {
  int blk = blockIdx.x;
  int b = blk / 28, strip = blk - b * 28;
  int r0 = strip * 4;
  int c = threadIdx.x;  // channel
  __shared__ float simg[3 * 9 * CW];
  const float* ib = img + (size_t)b * 3 * 224 * 224;
  for (int i = c; i < 3 * 9 * CW; i += 256) {
    int ch = i / (9 * CW);
    int rem = i - ch * (9 * CW);
    int lr = rem / CW;
    int col = rem - lr * CW;
    int ih = 2 * r0 - 1 + lr;
    int iw = col - 1;
    float v = 0.f;
    if (ih >= 0 && ih < 224 && iw >= 0) v = ib[((size_t)ch * 224 + ih) * 224 + iw];
    simg[i] = v;
  }
  float wr[27];
#pragma unroll
  for (int i = 0; i < 27; i++) wr[i] = w[c * 27 + i];
  __syncthreads();
  float s = 0.f, q = 0.f;
  for (int orow = 0; orow < 4; orow++) {
    int oh = r0 + orow;
    for (int ow = 0; ow < 112; ow++) {
      float acc = 0.f;
#pragma unroll
      for (int ch = 0; ch < 3; ch++)
#pragma unroll
        for (int dr = 0; dr < 3; dr++) {
          const float* rp = &simg[(ch * 9 + 2 * orow + dr) * CW + 2 * ow];
          acc = fmaf(wr[(ch * 3 + dr) * 3 + 0], rp[0], acc);
          acc = fmaf(wr[(ch * 3 + dr) * 3 + 1], rp[1], acc);
          acc = fmaf(wr[(ch * 3 + dr) * 3 + 2], rp[2], acc);
        }
      s += acc; q = fmaf(acc, acc, q);
      out[((size_t)(b * 112 + oh) * 112 + ow) * 256 + c] = f2bf(acc);
    }
  }
  atomicAdd(&stats[c], s);
  atomicAdd(&stats[256 + c], q);
}

// ---------------- bn1 finalize: par = {scale[C], shift[C]} ----------------
__global__ void k_bnfin(const float* __restrict__ stats, const float* __restrict__ g,
                        const float* __restrict__ bb, float* __restrict__ par, int C, float invN) {
  int c = blockIdx.x * 256 + threadIdx.x;
  if (c < C) {
    float m = stats[c] * invN;
    float v = stats[C + c] * invN - m * m;
    float sc = g[c] * rsqrtf(v + EPS);
    par[c] = sc;
    par[C + c] = bb[c] - m * sc;
  }
}

// ---------------- pw_w fp32 -> bf16 ----------------
__global__ void k_cvtbw(const float* __restrict__ w, u16* __restrict__ o, int n) {
  int i = blockIdx.x * 256 + threadIdx.x;
  if (i < n) o[i] = f2bf(w[i]);
}

// ---------------- fused dw(3x3, bn1+relu on read) + pw MFMA GEMM ----------------
// Block: 64 spatial rows x all 512 out channels. pass 0: per-channel sum/sumsq
// -> partials[blk][1024]. pass 1: bn2+relu+row-sum -> partials[blk][512].
__global__ __launch_bounds__(256, 2) void k_pwpass(
    const u16* __restrict__ conv1out, const float* __restrict__ bn1p,
    const float* __restrict__ dww, const u16* __restrict__ bwb,
    float* __restrict__ partials, const float* __restrict__ bn2p, int pass) {
  __shared__ u16 ash[64 * AP];
  int tid = threadIdx.x;
  int wave = tid >> 6;
  int lane = tid & 63;
  int m0 = blockIdx.x * 64;
  int bimg = blockIdx.x / 196;   // 196 blocks per image (12544/64)

  // ---- build A-tile: dw output for 64 positions x 256 channels ----
  {
    int c4 = lane * 4;
    float sc[4], sh[4], w9[4][9];
#pragma unroll
    for (int cc = 0; cc < 4; cc++) {
      sc[cc] = bn1p[c4 + cc];
      sh[cc] = bn1p[256 + c4 + cc];
#pragma unroll
      for (int i = 0; i < 9; i++) w9[cc][i] = dww[(c4 + cc) * 9 + i];
    }
    const u16* ib = conv1out + (size_t)bimg * S1 * 256;
    for (int pp = 0; pp < 16; pp++) {
      int p = wave * 16 + pp;                 // wave-uniform position
      int s = m0 + p - bimg * S1;
      int oh = s / 112, ow = s - oh * 112;
      float acc0 = 0.f, acc1 = 0.f, acc2 = 0.f, acc3 = 0.f;
#pragma unroll
      for (int dr = 0; dr < 3; dr++) {
        int ih = oh + dr - 1;
        if (ih < 0 || ih >= 112) continue;
#pragma unroll
        for (int dc = 0; dc < 3; dc++) {
          int iw = ow + dc - 1;
          if (iw < 0 || iw >= 112) continue;
          uint2 v = *(const uint2*)(ib + ((size_t)(ih * 112 + iw)) * 256 + c4);
          float x0, x1, x2, x3;
          bf2x2(v.x, x0, x1); bf2x2(v.y, x2, x3);
          int wi = dr * 3 + dc;
          acc0 = fmaf(w9[0][wi], fmaxf(fmaf(x0, sc[0], sh[0]), 0.f), acc0);
          acc1 = fmaf(w9[1][wi], fmaxf(fmaf(x1, sc[1], sh[1]), 0.f), acc1);
          acc2 = fmaf(w9[2][wi], fmaxf(fmaf(x2, sc[2], sh[2]), 0.f), acc2);
          acc3 = fmaf(w9[3][wi], fmaxf(fmaf(x3, sc[3], sh[3]), 0.f), acc3);
        }
      }
      union { u16 h[4]; uint2 v; } pk;
      pk.h[0] = f2bf(acc0); pk.h[1] = f2bf(acc1);
      pk.h[2] = f2bf(acc2); pk.h[3] = f2bf(acc3);
      *(uint2*)(&ash[p * AP + c4]) = pk.v;
    }
  }
  __syncthreads();

  // ---- MFMA GEMM: D[64 x 128-per-wave] over K=256 ----
  int quad = lane >> 4;
  int lr = lane & 15;
  int nbase = wave * 128;
  f32x4 acc[4][8];
#pragma unroll
  for (int mt = 0; mt < 4; mt++)
#pragma unroll
    for (int nt = 0; nt < 8; nt++) acc[mt][nt] = (f32x4){0.f, 0.f, 0.f, 0.f};

  for (int kk = 0; kk < 256; kk += 32) {
    bf16x8 af[4];
#pragma unroll
    for (int mt = 0; mt < 4; mt++)
      af[mt] = *(const bf16x8*)(&ash[(mt * 16 + lr) * AP + kk + quad * 8]);
    bf16x8 bfr[8];
#pragma unroll
    for (int nt = 0; nt < 8; nt++)
      bfr[nt] = *(const bf16x8*)(bwb + (size_t)(nbase + nt * 16 + lr) * 256 + kk + quad * 8);
#pragma unroll
    for (int mt = 0; mt < 4; mt++)
#pragma unroll
      for (int nt = 0; nt < 8; nt++)
        acc[mt][nt] = __builtin_amdgcn_mfma_f32_16x16x32_bf16(af[mt], bfr[nt], acc[mt][nt], 0, 0, 0);
  }

  if (pass == 0) {
#pragma unroll
    for (int nt = 0; nt < 8; nt++) {
      float s = 0.f, q = 0.f;
#pragma unroll
      for (int mt = 0; mt < 4; mt++)
#pragma unroll
        for (int r = 0; r < 4; r++) {
          float v = acc[mt][nt][r];
          s += v; q = fmaf(v, v, q);
        }
      s += __shfl_xor(s, 16); s += __shfl_xor(s, 32);
      q += __shfl_xor(q, 16); q += __shfl_xor(q, 32);
      if (lane < 16) {
        int n = nbase + nt * 16 + lane;
        partials[(size_t)blockIdx.x * 1024 + n] = s;
        partials[(size_t)blockIdx.x * 1024 + 512 + n] = q;
      }
    }
  } else {
#pragma unroll
    for (int nt = 0; nt < 8; nt++) {
      int n = nbase + nt * 16 + lr;
      float scn = bn2p[n], shn = bn2p[512 + n];
      float s = 0.f;
#pragma unroll
      for (int mt = 0; mt < 4; mt++)
#pragma unroll
        for (int r = 0; r < 4; r++)
          s += fmaxf(fmaf(acc[mt][nt][r], scn, shn), 0.f);
      s += __shfl_xor(s, 16); s += __shfl_xor(s, 32);
      if (lane < 16)
        partials[(size_t)blockIdx.x * 512 + n] = s;
    }
  }
}

// ---------------- reduce pass-0 partials -> bn2 scale/shift ----------------
__global__ void k_red_bn(const float* __restrict__ P, const float* __restrict__ g,
                         const float* __restrict__ bb, float* __restrict__ par) {
  int c = blockIdx.x * 256 + threadIdx.x;  // 0..511
  float s = 0.f, q = 0.f;
  for (int i = 0; i < 3136; i++) {
    s += P[(size_t)i * 1024 + c];
    q += P[(size_t)i * 1024 + 512 + c];
  }
  float m = s * (1.f / (float)NSTAT);
  float v = q * (1.f / (float)NSTAT) - m * m;
  float sc = g[c] * rsqrtf(v + EPS);
  par[c] = sc;
  par[512 + c] = bb[c] - m * sc;
}

// ---------------- reduce pass-1 partials -> y[b][c] (un-normalized spatial sum) ----------------
__global__ void k_red_y(const float* __restrict__ P, float* __restrict__ yb) {
  int idx = blockIdx.x * 256 + threadIdx.x;  // 0..8191
  int b = idx >> 9, c = idx & 511;
  float s = 0.f;
  for (int i = 0; i < 196; i++) s += P[(size_t)(b * 196 + i) * 512 + c];
  yb[idx] = s;
}

// ---------------- per-batch SE + enc_fc + ctx + ctx-part of gi ----------------
__global__ __launch_bounds__(256) void k_se(const float* __restrict__ y,
    const float* __restrict__ se1, const float* __restrict__ se2,
    const float* __restrict__ encw, const float* __restrict__ encb,
    const float* __restrict__ vw, const float* __restrict__ wih,
    const float* __restrict__ bih, float* __restrict__ ctxgi) {
  int b = blockIdx.x;
  int t = threadIdx.x;
  __shared__ __align__(16) float ybar[512];
  __shared__ __align__(16) float uu[128];
  __shared__ __align__(16) float ff[512];
  __shared__ __align__(16) float feats[512];
  __shared__ __align__(16) float ctx[512];
  for (int i = t; i < 512; i += 256) ybar[i] = y[b * 512 + i] * (1.f / 12544.f);
  __syncthreads();
  if (t < 128) {
    const float4* wr = (const float4*)(se1 + t * 512);
    const float4* xv = (const float4*)ybar;
    float a = 0.f;
    for (int k = 0; k < 128; k++) {
      float4 w4 = wr[k], x4 = xv[k];
      a = fmaf(w4.x, x4.x, a); a = fmaf(w4.y, x4.y, a);
      a = fmaf(w4.z, x4.z, a); a = fmaf(w4.w, x4.w, a);
    }
    uu[t] = fmaxf(a, 0.f);
  }
  __syncthreads();
  for (int c = t; c < 512; c += 256) {
    const float4* wr = (const float4*)(se2 + c * 128);
    const float4* xv = (const float4*)uu;
    float a = 0.f;
    for (int k = 0; k < 32; k++) {
      float4 w4 = wr[k], x4 = xv[k];
      a = fmaf(w4.x, x4.x, a); a = fmaf(w4.y, x4.y, a);
      a = fmaf(w4.z, x4.z, a); a = fmaf(w4.w, x4.w, a);
    }
    ff[c] = ybar[c] / (1.f + expf(-a));
  }
  __syncthreads();
  for (int c = t; c < 512; c += 256) {
    const float4* wr = (const float4*)(encw + (size_t)c * 512);
    const float4* xv = (const float4*)ff;
    float a = encb[c];
    for (int k = 0; k < 128; k++) {
      float4 w4 = wr[k], x4 = xv[k];
      a = fmaf(w4.x, x4.x, a); a = fmaf(w4.y, x4.y, a);
      a = fmaf(w4.z, x4.z, a); a = fmaf(w4.w, x4.w, a);
    }
    feats[c] = a;
  }
  __syncthreads();
  for (int c = t; c < 512; c += 256) {
    const float4* wr = (const float4*)(vw + (size_t)c * 512);
    const float4* xv = (const float4*)feats;
    float a = 0.f;
    for (int k = 0; k < 128; k++) {
      float4 w4 = wr[k], x4 = xv[k];
      a = fmaf(w4.x, x4.x, a); a = fmaf(w4.y, x4.y, a);
      a = fmaf(w4.z, x4.z, a); a = fmaf(w4.w, x4.w, a);
    }
    ctx[c] = a;
  }
  __syncthreads();
  for (int j = t; j < 1536; j += 256) {
    const float4* wr = (const float4*)(wih + (size_t)j * 1024 + 512);
    const float4* xv = (const float4*)ctx;
    float a = bih[j];
    for (int k = 0; k < 128; k++) {
      float4 w4 = wr[k], x4 = xv[k];
      a = fmaf(w4.x, x4.x, a); a = fmaf(w4.y, x4.y, a);
      a = fmaf(w4.z, x4.z, a); a = fmaf(w4.w, x4.w, a);
    }
    ctxgi[b * 1536 + j] = a;
  }
}

// ---------------- gi = emb @ w_ih[:, :512]^T + ctxgi  (layout [t][b][j]) ----------------
__global__ __launch_bounds__(256) void k_gi(const int* __restrict__ caps, const float* __restrict__ embed,
    const float* __restrict__ wih, const float* __restrict__ ctxgi, float* __restrict__ gi) {
  int tt = blockIdx.x;   // time 0..31
  int jt = blockIdx.y;   // j tile 0..95
  int lb = threadIdx.x / 16;
  int lj = threadIdx.x % 16;
  int j = jt * 16 + lj;
  __shared__ __align__(16) float em[16][512];
  for (int i = threadIdx.x; i < 16 * 512; i += 256) {
    int bb = i / 512, k = i - bb * 512;
    int tok = caps[bb * 33 + tt];
    em[bb][k] = embed[(size_t)tok * 512 + k];
  }
  __syncthreads();
  const float4* wr = (const float4*)(wih + (size_t)j * 1024);
  const float4* er = (const float4*)em[lb];
  float a = 0.f;
#pragma unroll 4
  for (int k = 0; k < 128; k++) {
    float4 w4 = wr[k], e4 = er[k];
    a = fmaf(w4.x, e4.x, a); a = fmaf(w4.y, e4.y, a);
    a = fmaf(w4.z, e4.z, a); a = fmaf(w4.w, e4.w, a);
  }
  gi[((size_t)tt * 16 + lb) * 1536 + j] = a + ctxgi[lb * 1536 + j];
}

// ---------------- one GRU step: h_all[t] -> h_all[t+1] ----------------
// 32 blocks x 256 threads: block g covers hidden units jj = g*16 + (tid%16) in [0,512)
__global__ __launch_bounds__(256) void k_gru(const float* __restrict__ whh, const float* __restrict__ bhh,
    const float* __restrict__ gi, float* __restrict__ h_all, int t) {
  int g = blockIdx.x;
  int lb = threadIdx.x / 16, lj = threadIdx.x % 16;
  int jj = g * 16 + lj;   // [0,512)
  const float* hprev = h_all + (size_t)t * 8192;
  float* hnew = h_all + (size_t)(t + 1) * 8192;
  __shared__ __align__(16) float hs[16][512];
  for (int i = threadIdx.x; i < 8192; i += 256) hs[i / 512][i & 511] = hprev[i];
  __syncthreads();
  const float4* hv = (const float4*)hs[lb];
  float d[3];
#pragma unroll
  for (int gate = 0; gate < 3; gate++) {
    const float4* wr = (const float4*)(whh + (size_t)(jj + gate * 512) * 512);
    float a = 0.f;
#pragma unroll 4
    for (int k = 0; k < 128; k++) {
      float4 w4 = wr[k], h4 = hv[k];
      a = fmaf(w4.x, h4.x, a); a = fmaf(w4.y, h4.y, a);
      a = fmaf(w4.z, h4.z, a); a = fmaf(w4.w, h4.w, a);
    }
    d[gate] = a;
  }
  const float* gib = gi + ((size_t)t * 16 + lb) * 1536;
  float ir = gib[jj], iz = gib[jj + 512], inn = gib[jj + 1024];
  float hr = d[0] + bhh[jj], hz = d[1] + bhh[jj + 512], hn = d[2] + bhh[jj + 1024];
  float r = 1.f / (1.f + expf(-(ir + hr)));
  float z = 1.f / (1.f + expf(-(iz + hz)));
  float n = tanhf(inn + r * hn);
  float hp = hs[lb][jj];
  hnew[lb * 512 + jj] = (1.f - z) * n + z * hp;
}

// ---------------- logits GEMM: [512,512] x [32000,512]^T + bias, permuted rows ----------------
__global__ __launch_bounds__(256) void k_fc(const float* __restrict__ A, const float* __restrict__ Bw,
    const float* __restrict__ bias, float* __restrict__ out) {
  __shared__ float As[16][128];
  __shared__ float Bs[16][128];
  int nt = blockIdx.x, mt = blockIdx.y;
  int n0 = nt * 128, m0 = mt * 128;
  int tid = threadIdx.x;
  int tx = tid % 16, ty = tid / 16;
  int lm = tid >> 1;
  int lk = (tid & 1) * 8;
  float acc[8][8] = {};
  for (int kt = 0; kt < 512; kt += 16) {
    const float4* ap = (const float4*)(A + (size_t)(m0 + lm) * 512 + kt + lk);
    float4 a0 = ap[0], a1 = ap[1];
    const float4* bp = (const float4*)(Bw + (size_t)(n0 + lm) * 512 + kt + lk);
    float4 b0 = bp[0], b1 = bp[1];
    As[lk + 0][lm] = a0.x; As[lk + 1][lm] = a0.y; As[lk + 2][lm] = a0.z; As[lk + 3][lm] = a0.w;
    As[lk + 4][lm] = a1.x; As[lk + 5][lm] = a1.y; As[lk + 6][lm] = a1.z; As[lk + 7][lm] = a1.w;
    Bs[lk + 0][lm] = b0.x; Bs[lk + 1][lm] = b0.y; Bs[lk + 2][lm] = b0.z; Bs[lk + 3][lm] = b0.w;
    Bs[lk + 4][lm] = b1.x; Bs[lk + 5][lm] = b1.y; Bs[lk + 6][lm] = b1.z; Bs[lk + 7][lm] = b1.w;
    __syncthreads();
#pragma unroll
    for (int k = 0; k < 16; k++) {
      float a[8], bb[8];
      *(float4*)&a[0] = *(const float4*)&As[k][ty * 8];
      *(float4*)&a[4] = *(const float4*)&As[k][ty * 8 + 4];
      *(float4*)&bb[0] = *(const float4*)&Bs[k][tx * 8];
      *(float4*)&bb[4] = *(const float4*)&Bs[k][tx * 8 + 4];
#pragma unroll
      for (int i = 0; i < 8; i++)
#pragma unroll
        for (int j = 0; j < 8; j++)
          acc[i][j] = fmaf(a[i], bb[j], acc[i][j]);
    }
    __syncthreads();
  }
  int j0 = n0 + tx * 8;
  float bv[8];
#pragma unroll
  for (int j = 0; j < 8; j++) bv[j] = bias[j0 + j];
  for (int i = 0; i < 8; i++) {
    int m = m0 + ty * 8 + i;               // m = t*16 + b
    int orow = (m & 15) * 32 + (m >> 4);   // out row = b*32 + t
    float4 r0, r1;
    r0.x = acc[i][0] + bv[0]; r0.y = acc[i][1] + bv[1];
    r0.z = acc[i][2] + bv[2]; r0.w = acc[i][3] + bv[3];
    r1.x = acc[i][4] + bv[4]; r1.y = acc[i][5] + bv[5];
    r1.z = acc[i][6] + bv[6]; r1.w = acc[i][7] + bv[7];
    *(float4*)(out + (size_t)orow * 32000 + j0) = r0;
    *(float4*)(out + (size_t)orow * 32000 + j0 + 4) = r1;
  }
}

extern "C" void kernel_launch(void* const* d_in, const int* in_sizes, int n_in,
                              void* d_out, int out_size, void* d_ws, size_t ws_size,
                              hipStream_t stream) {
  const float* images  = (const float*)d_in[0];
  const int*   caps    = (const int*)d_in[1];
  const float* conv1_w = (const float*)d_in[2];
  const float* bn1_g   = (const float*)d_in[3];
  const float* bn1_b   = (const float*)d_in[4];
  const float* dw_w    = (const float*)d_in[5];
  const float* pw_w    = (const float*)d_in[6];
  const float* bn2_g   = (const float*)d_in[7];
  const float* bn2_b   = (const float*)d_in[8];
  const float* se1     = (const float*)d_in[9];
  const float* se2     = (const float*)d_in[10];
  const float* encw    = (const float*)d_in[11];
  const float* encb    = (const float*)d_in[12];
  const float* embed   = (const float*)d_in[13];
  // d_in[14]=q_w, d_in[15]=k_w are unused by the reference
  const float* vw      = (const float*)d_in[16];
  const float* wih     = (const float*)d_in[17];
  const float* whh     = (const float*)d_in[18];
  const float* bih     = (const float*)d_in[19];
  const float* bhh     = (const float*)d_in[20];
  const float* fcw     = (const float*)d_in[21];
  const float* fcb     = (const float*)d_in[22];
  float* out = (float*)d_out;

  // ---- workspace (~120 MB peak) ----
  char* ws = (char*)d_ws;
  size_t off = 0;
  auto alloc = [&](size_t bytes) {
    void* p = ws + off;
    off = (off + bytes + 255) & ~(size_t)255;
    return p;
  };
  u16*   conv1out = (u16*)alloc((size_t)51380224 * 2);        // 98 MB bf16 NHWC
  u16*   bwb      = (u16*)alloc((size_t)131072 * 2);          // pw_w bf16
  float* partials = (float*)alloc((size_t)3136 * 1024 * 4);   // 12.8 MB
  float* stats1   = (float*)alloc(512 * 4);
  float* h_all    = (float*)alloc((size_t)33 * 8192 * 4);
  float* bn1p     = (float*)alloc(512 * 4);
  float* bn2p     = (float*)alloc(1024 * 4);
  float* yb       = (float*)alloc(8192 * 4);
  float* ctxgi    = (float*)alloc((size_t)16 * 1536 * 4);
  float* gi       = (float*)alloc((size_t)32 * 16 * 1536 * 4);
  (void)ws_size; (void)in_sizes; (void)n_in; (void)out_size;

  hipMemsetAsync(stats1, 0, 512 * 4, stream);
  hipMemsetAsync(h_all, 0, 8192 * 4, stream);   // h0 = 0

  k_conv1<<<448, 256, 0, stream>>>(images, conv1_w, conv1out, stats1);
  k_bnfin<<<1, 256, 0, stream>>>(stats1, bn1_g, bn1_b, bn1p, 256, 1.f / (float)NSTAT);
  k_cvtbw<<<512, 256, 0, stream>>>(pw_w, bwb, 131072);
  k_pwpass<<<3136, 256, 0, stream>>>(conv1out, bn1p, dw_w, bwb, partials, bn2p, 0);
  k_red_bn<<<2, 256, 0, stream>>>(partials, bn2_g, bn2_b, bn2p);
  k_pwpass<<<3136, 256, 0, stream>>>(conv1out, bn1p, dw_w, bwb, partials, bn2p, 1);
  k_red_y<<<32, 256, 0, stream>>>(partials, yb);
  k_se<<<16, 256, 0, stream>>>(yb, se1, se2, encw, encb, vw, wih, bih, ctxgi);
  dim3 ggi(32, 96);
  k_gi<<<ggi, 256, 0, stream>>>(caps, embed, wih, ctxgi, gi);
  for (int t = 0; t < 32; t++)
    k_gru<<<32, 256, 0, stream>>>(whh, bhh, gi, h_all, t);
  dim3 gfc(250, 4);
  k_fc<<<gfc, 256, 0, stream>>>(h_all + 8192, fcw, fcb, out);
}

// Round 4
// 2631.364 us; speedup vs baseline: 1.2118x; 1.2118x over previous
//
#include <hip/hip_runtime.h>

typedef unsigned int u32;
typedef unsigned short u16;
typedef short bf16x8 __attribute__((ext_vector_type(8)));
typedef float f32x4 __attribute__((ext_vector_type(4)));

#define S1 12544      // 112*112
#define NSTAT 200704  // 16*112*112
#define EPS 1e-5f
#define AP 264        // padded A-tile row length in bf16 elems (256 + 8)

__device__ __forceinline__ u16 f2bf(float f) {
  union { float f; u32 u; } x; x.f = f;
  u32 r = x.u + 0x7fffu + ((x.u >> 16) & 1u);
  return (u16)(r >> 16);
}
__device__ __forceinline__ void bf2x2(u32 u, float& lo, float& hi) {
  union { u32 u; float f; } a, b;
  a.u = u << 16; b.u = u & 0xffff0000u;
  lo = a.f; hi = b.f;
}

// ---------------- conv1 (3->256, 3x3, stride2, pad1) + bn1 stats ----------------
// 896 blocks: 16 images x 56 two-row strips
#define CW 225
__global__ __launch_bounds__(256) void k_conv1(const float* __restrict__ img,
    const float* __restrict__ w, u16* __restrict__ out, float* __restrict__ stats) {
  int blk = blockIdx.x;
  int b = blk / 56, strip = blk - b * 56;
  int r0 = strip * 2;
  int c = threadIdx.x;  // channel
  __shared__ float simg[3 * 5 * CW];
  const float* ib = img + (size_t)b * 3 * 224 * 224;
  for (int i = c; i < 3 * 5 * CW; i += 256) {
    int ch = i / (5 * CW);
    int rem = i - ch * (5 * CW);
    int lr = rem / CW;
    int col = rem - lr * CW;
    int ih = 2 * r0 - 1 + lr;
    int iw = col - 1;
    float v = 0.f;
    if (ih >= 0 && ih < 224 && iw >= 0 && iw < 224) v = ib[((size_t)ch * 224 + ih) * 224 + iw];
    simg[i] = v;
  }
  float wr[27];
#pragma unroll
  for (int i = 0; i < 27; i++) wr[i] = w[c * 27 + i];
  __syncthreads();
  float s = 0.f, q = 0.f;
  for (int orow = 0; orow < 2; orow++) {
    int oh = r0 + orow;
    for (int ow = 0; ow < 112; ow++) {
      float acc = 0.f;
#pragma unroll
      for (int ch = 0; ch < 3; ch++)
#pragma unroll
        for (int dr = 0; dr < 3; dr++) {
          const float* rp = &simg[(ch * 5 + 2 * orow + dr) * CW + 2 * ow];
          acc = fmaf(wr[(ch * 3 + dr) * 3 + 0], rp[0], acc);
          acc = fmaf(wr[(ch * 3 + dr) * 3 + 1], rp[1], acc);
          acc = fmaf(wr[(ch * 3 + dr) * 3 + 2], rp[2], acc);
        }
      s += acc; q = fmaf(acc, acc, q);
      out[((size_t)(b * 112 + oh) * 112 + ow) * 256 + c] = f2bf(acc);
    }
  }
  atomicAdd(&stats[c], s);
  atomicAdd(&stats[256 + c], q);
}

// ---------------- bn1 finalize: par = {scale[C], shift[C]} ----------------
__global__ void k_bnfin(const float* __restrict__ stats, const float* __restrict__ g,
                        const float* __restrict__ bb, float* __restrict__ par, int C, float invN) {
  int c = blockIdx.x * 256 + threadIdx.x;
  if (c < C) {
    float m = stats[c] * invN;
    float v = stats[C + c] * invN - m * m;
    float sc = g[c] * rsqrtf(v + EPS);
    par[c] = sc;
    par[C + c] = bb[c] - m * sc;
  }
}

// ---------------- fp32 -> bf16, 4 at a time ----------------
__global__ void k_cvt4(const float* __restrict__ w, u16* __restrict__ o, int n4) {
  int i = blockIdx.x * 256 + threadIdx.x;
  if (i < n4) {
    float4 v = ((const float4*)w)[i];
    union { u16 h[4]; uint2 u; } pk;
    pk.h[0] = f2bf(v.x); pk.h[1] = f2bf(v.y); pk.h[2] = f2bf(v.z); pk.h[3] = f2bf(v.w);
    ((uint2*)o)[i] = pk.u;
  }
}

// ---------------- fused dw(3x3, bn1+relu on read) + pw MFMA GEMM ----------------
// Block: 64 spatial rows x all 512 out channels. pass 0: per-channel sum/sumsq
// -> partials[blk][1024]. pass 1: bn2+relu+row-sum -> partials[blk][512].
// A-build uses a sliding 3x3 post-activation register window: 3 loads/position.
#define LD_COL(ohv, iwv, slot) do {                                          \
    int _oh = (ohv), _iw = (iwv);                                            \
  _Pragma("unroll")                                                          \
    for (int _dr = 0; _dr < 3; _dr++) {                                      \
      int _ih = _oh - 1 + _dr;                                               \
      float _x0 = 0.f, _x1 = 0.f, _x2 = 0.f, _x3 = 0.f;                      \
      if (_ih >= 0 && _ih < 112 && _iw >= 0 && _iw < 112) {                  \
        uint2 _v = *(const uint2*)(ib + ((size_t)(_ih * 112 + _iw)) * 256 + c4); \
        float _t0, _t1, _t2, _t3;                                            \
        bf2x2(_v.x, _t0, _t1); bf2x2(_v.y, _t2, _t3);                        \
        _x0 = fmaxf(fmaf(_t0, sc[0], sh[0]), 0.f);                           \
        _x1 = fmaxf(fmaf(_t1, sc[1], sh[1]), 0.f);                           \
        _x2 = fmaxf(fmaf(_t2, sc[2], sh[2]), 0.f);                           \
        _x3 = fmaxf(fmaf(_t3, sc[3], sh[3]), 0.f);                           \
      }                                                                      \
      act[_dr][slot][0] = _x0; act[_dr][slot][1] = _x1;                      \
      act[_dr][slot][2] = _x2; act[_dr][slot][3] = _x3;                      \
    }                                                                        \
  } while (0)

__global__ __launch_bounds__(256, 2) void k_pwpass(
    const u16* __restrict__ conv1out, const float* __restrict__ bn1p,
    const float* __restrict__ dww, const u16* __restrict__ bwb,
    float* __restrict__ partials, const float* __restrict__ bn2p, int pass) {
  __shared__ u16 ash[64 * AP];
  int tid = threadIdx.x;
  int wave = tid >> 6;
  int lane = tid & 63;
  int m0 = blockIdx.x * 64;
  int bimg = blockIdx.x / 196;   // 196 blocks per image (12544/64)

  // ---- build A-tile: dw output for 64 positions x 256 channels ----
  {
    int c4 = lane * 4;
    float sc[4], sh[4], w9[4][9];
#pragma unroll
    for (int cc = 0; cc < 4; cc++) {
      sc[cc] = bn1p[c4 + cc];
      sh[cc] = bn1p[256 + c4 + cc];
#pragma unroll
      for (int i = 0; i < 9; i++) w9[cc][i] = dww[(c4 + cc) * 9 + i];
    }
    const u16* ib = conv1out + (size_t)bimg * S1 * 256;
    float act[3][3][4];   // [row][col-slot][ch], post bn1+relu (0 outside image)
#pragma unroll
    for (int pp = 0; pp < 16; pp++) {
      int p = wave * 16 + pp;                 // wave-uniform position
      int s = m0 + p - bimg * S1;
      int oh = s / 112, ow = s - oh * 112;
      if (pp == 0 || ow == 0) {               // wave-uniform branch
        LD_COL(oh, ow - 1, (pp + 0) % 3);
        LD_COL(oh, ow,     (pp + 1) % 3);
        LD_COL(oh, ow + 1, (pp + 2) % 3);
      } else {
        LD_COL(oh, ow + 1, (pp + 2) % 3);
      }
      float a0 = 0.f, a1 = 0.f, a2 = 0.f, a3 = 0.f;
#pragma unroll
      for (int dr = 0; dr < 3; dr++)
#pragma unroll
        for (int dc = 0; dc < 3; dc++) {
          const int sl = (pp + dc) % 3;
          const int wi = dr * 3 + dc;
          a0 = fmaf(w9[0][wi], act[dr][sl][0], a0);
          a1 = fmaf(w9[1][wi], act[dr][sl][1], a1);
          a2 = fmaf(w9[2][wi], act[dr][sl][2], a2);
          a3 = fmaf(w9[3][wi], act[dr][sl][3], a3);
        }
      union { u16 h[4]; uint2 v; } pk;
      pk.h[0] = f2bf(a0); pk.h[1] = f2bf(a1);
      pk.h[2] = f2bf(a2); pk.h[3] = f2bf(a3);
      *(uint2*)(&ash[p * AP + c4]) = pk.v;
    }
  }
  __syncthreads();

  // ---- MFMA GEMM: D[64 x 128-per-wave] over K=256 ----
  int quad = lane >> 4;
  int lr = lane & 15;
  int nbase = wave * 128;
  f32x4 acc[4][8];
#pragma unroll
  for (int mt = 0; mt < 4; mt++)
#pragma unroll
    for (int nt = 0; nt < 8; nt++) acc[mt][nt] = (f32x4){0.f, 0.f, 0.f, 0.f};

  for (int kk = 0; kk < 256; kk += 32) {
    bf16x8 af[4];
#pragma unroll
    for (int mt = 0; mt < 4; mt++)
      af[mt] = *(const bf16x8*)(&ash[(mt * 16 + lr) * AP + kk + quad * 8]);
    bf16x8 bfr[8];
#pragma unroll
    for (int nt = 0; nt < 8; nt++)
      bfr[nt] = *(const bf16x8*)(bwb + (size_t)(nbase + nt * 16 + lr) * 256 + kk + quad * 8);
#pragma unroll
    for (int mt = 0; mt < 4; mt++)
#pragma unroll
      for (int nt = 0; nt < 8; nt++)
        acc[mt][nt] = __builtin_amdgcn_mfma_f32_16x16x32_bf16(af[mt], bfr[nt], acc[mt][nt], 0, 0, 0);
  }

  if (pass == 0) {
#pragma unroll
    for (int nt = 0; nt < 8; nt++) {
      float s = 0.f, q = 0.f;
#pragma unroll
      for (int mt = 0; mt < 4; mt++)
#pragma unroll
        for (int r = 0; r < 4; r++) {
          float v = acc[mt][nt][r];
          s += v; q = fmaf(v, v, q);
        }
      s += __shfl_xor(s, 16); s += __shfl_xor(s, 32);
      q += __shfl_xor(q, 16); q += __shfl_xor(q, 32);
      if (lane < 16) {
        int n = nbase + nt * 16 + lane;
        partials[(size_t)blockIdx.x * 1024 + n] = s;
        partials[(size_t)blockIdx.x * 1024 + 512 + n] = q;
      }
    }
  } else {
#pragma unroll
    for (int nt = 0; nt < 8; nt++) {
      int n = nbase + nt * 16 + lr;
      float scn = bn2p[n], shn = bn2p[512 + n];
      float s = 0.f;
#pragma unroll
      for (int mt = 0; mt < 4; mt++)
#pragma unroll
        for (int r = 0; r < 4; r++)
          s += fmaxf(fmaf(acc[mt][nt][r], scn, shn), 0.f);
      s += __shfl_xor(s, 16); s += __shfl_xor(s, 32);
      if (lane < 16)
        partials[(size_t)blockIdx.x * 512 + n] = s;
    }
  }
}

// ---------------- stage-1 reduce of pass-0 partials: 3136 rows -> 64 rows ----------------
__global__ __launch_bounds__(256) void k_red1(const float* __restrict__ P, float* __restrict__ P2) {
  int blk = blockIdx.x;   // 0..63
  int t = threadIdx.x;
  float4 s = {0.f, 0.f, 0.f, 0.f};
  for (int r = 0; r < 49; r++) {
    float4 v = *(const float4*)(P + ((size_t)(blk * 49 + r)) * 1024 + t * 4);
    s.x += v.x; s.y += v.y; s.z += v.z; s.w += v.w;
  }
  *(float4*)(P2 + (size_t)blk * 1024 + t * 4) = s;
}

// ---------------- stage-2: 64 rows -> bn2 scale/shift ----------------
__global__ void k_red_bn2(const float* __restrict__ P2, const float* __restrict__ g,
                          const float* __restrict__ bb, float* __restrict__ par) {
  int c = blockIdx.x * 256 + threadIdx.x;  // 0..511
  float s = 0.f, q = 0.f;
  for (int i = 0; i < 64; i++) {
    s += P2[(size_t)i * 1024 + c];
    q += P2[(size_t)i * 1024 + 512 + c];
  }
  float m = s * (1.f / (float)NSTAT);
  float v = q * (1.f / (float)NSTAT) - m * m;
  float sc = g[c] * rsqrtf(v + EPS);
  par[c] = sc;
  par[512 + c] = bb[c] - m * sc;
}

// ---------------- reduce pass-1 partials -> y[b][c] (un-normalized spatial sum) ----------------
__global__ void k_red_y(const float* __restrict__ P, float* __restrict__ yb) {
  int idx = blockIdx.x * 256 + threadIdx.x;  // 0..8191
  int b = idx >> 9, c = idx & 511;
  float s = 0.f;
  for (int i = 0; i < 196; i++) s += P[(size_t)(b * 196 + i) * 512 + c];
  yb[idx] = s;
}

// ---------------- per-batch SE + enc_fc + ctx + ctx-part of gi ----------------
__global__ __launch_bounds__(256) void k_se(const float* __restrict__ y,
    const float* __restrict__ se1, const float* __restrict__ se2,
    const float* __restrict__ encw, const float* __restrict__ encb,
    const float* __restrict__ vw, const float* __restrict__ wih,
    const float* __restrict__ bih, float* __restrict__ ctxgi) {
  int b = blockIdx.x;
  int t = threadIdx.x;
  __shared__ __align__(16) float ybar[512];
  __shared__ __align__(16) float uu[128];
  __shared__ __align__(16) float ff[512];
  __shared__ __align__(16) float feats[512];
  __shared__ __align__(16) float ctx[512];
  for (int i = t; i < 512; i += 256) ybar[i] = y[b * 512 + i] * (1.f / 12544.f);
  __syncthreads();
  if (t < 128) {
    const float4* wr = (const float4*)(se1 + t * 512);
    const float4* xv = (const float4*)ybar;
    float a = 0.f;
    for (int k = 0; k < 128; k++) {
      float4 w4 = wr[k], x4 = xv[k];
      a = fmaf(w4.x, x4.x, a); a = fmaf(w4.y, x4.y, a);
      a = fmaf(w4.z, x4.z, a); a = fmaf(w4.w, x4.w, a);
    }
    uu[t] = fmaxf(a, 0.f);
  }
  __syncthreads();
  for (int c = t; c < 512; c += 256) {
    const float4* wr = (const float4*)(se2 + c * 128);
    const float4* xv = (const float4*)uu;
    float a = 0.f;
    for (int k = 0; k < 32; k++) {
      float4 w4 = wr[k], x4 = xv[k];
      a = fmaf(w4.x, x4.x, a); a = fmaf(w4.y, x4.y, a);
      a = fmaf(w4.z, x4.z, a); a = fmaf(w4.w, x4.w, a);
    }
    ff[c] = ybar[c] / (1.f + expf(-a));
  }
  __syncthreads();
  for (int c = t; c < 512; c += 256) {
    const float4* wr = (const float4*)(encw + (size_t)c * 512);
    const float4* xv = (const float4*)ff;
    float a = encb[c];
    for (int k = 0; k < 128; k++) {
      float4 w4 = wr[k], x4 = xv[k];
      a = fmaf(w4.x, x4.x, a); a = fmaf(w4.y, x4.y, a);
      a = fmaf(w4.z, x4.z, a); a = fmaf(w4.w, x4.w, a);
    }
    feats[c] = a;
  }
  __syncthreads();
  for (int c = t; c < 512; c += 256) {
    const float4* wr = (const float4*)(vw + (size_t)c * 512);
    const float4* xv = (const float4*)feats;
    float a = 0.f;
    for (int k = 0; k < 128; k++) {
      float4 w4 = wr[k], x4 = xv[k];
      a = fmaf(w4.x, x4.x, a); a = fmaf(w4.y, x4.y, a);
      a = fmaf(w4.z, x4.z, a); a = fmaf(w4.w, x4.w, a);
    }
    ctx[c] = a;
  }
  __syncthreads();
  for (int j = t; j < 1536; j += 256) {
    const float4* wr = (const float4*)(wih + (size_t)j * 1024 + 512);
    const float4* xv = (const float4*)ctx;
    float a = bih[j];
    for (int k = 0; k < 128; k++) {
      float4 w4 = wr[k], x4 = xv[k];
      a = fmaf(w4.x, x4.x, a); a = fmaf(w4.y, x4.y, a);
      a = fmaf(w4.z, x4.z, a); a = fmaf(w4.w, x4.w, a);
    }
    ctxgi[b * 1536 + j] = a;
  }
}

// ---------------- gi = emb @ w_ih[:, :512]^T + ctxgi  (layout [t][b][j]) ----------------
__global__ __launch_bounds__(256) void k_gi(const int* __restrict__ caps, const float* __restrict__ embed,
    const float* __restrict__ wih, const float* __restrict__ ctxgi, float* __restrict__ gi) {
  int tt = blockIdx.x;   // time 0..31
  int jt = blockIdx.y;   // j tile 0..95
  int lb = threadIdx.x / 16;
  int lj = threadIdx.x % 16;
  int j = jt * 16 + lj;
  __shared__ __align__(16) float em[16][512];
  for (int i = threadIdx.x; i < 16 * 512; i += 256) {
    int bb = i / 512, k = i - bb * 512;
    int tok = caps[bb * 33 + tt];
    em[bb][k] = embed[(size_t)tok * 512 + k];
  }
  __syncthreads();
  const float4* wr = (const float4*)(wih + (size_t)j * 1024);
  const float4* er = (const float4*)em[lb];
  float a = 0.f;
#pragma unroll 4
  for (int k = 0; k < 128; k++) {
    float4 w4 = wr[k], e4 = er[k];
    a = fmaf(w4.x, e4.x, a); a = fmaf(w4.y, e4.y, a);
    a = fmaf(w4.z, e4.z, a); a = fmaf(w4.w, e4.w, a);
  }
  gi[((size_t)tt * 16 + lb) * 1536 + j] = a + ctxgi[lb * 1536 + j];
}

// ---------------- one GRU step: h_all[t] -> h_all[t+1] ----------------
// 32 blocks x 256 threads: block g covers hidden units jj = g*16 + (tid%16) in [0,512)
__global__ __launch_bounds__(256) void k_gru(const float* __restrict__ whh, const float* __restrict__ bhh,
    const float* __restrict__ gi, float* __restrict__ h_all, int t) {
  int g = blockIdx.x;
  int lb = threadIdx.x / 16, lj = threadIdx.x % 16;
  int jj = g * 16 + lj;   // [0,512)
  const float* hprev = h_all + (size_t)t * 8192;
  float* hnew = h_all + (size_t)(t + 1) * 8192;
  __shared__ __align__(16) float hs[16][512];
  for (int i = threadIdx.x; i < 8192; i += 256) hs[i / 512][i & 511] = hprev[i];
  __syncthreads();
  const float4* hv = (const float4*)hs[lb];
  float d[3];
#pragma unroll
  for (int gate = 0; gate < 3; gate++) {
    const float4* wr = (const float4*)(whh + (size_t)(jj + gate * 512) * 512);
    float a = 0.f;
#pragma unroll 4
    for (int k = 0; k < 128; k++) {
      float4 w4 = wr[k], h4 = hv[k];
      a = fmaf(w4.x, h4.x, a); a = fmaf(w4.y, h4.y, a);
      a = fmaf(w4.z, h4.z, a); a = fmaf(w4.w, h4.w, a);
    }
    d[gate] = a;
  }
  const float* gib = gi + ((size_t)t * 16 + lb) * 1536;
  float ir = gib[jj], iz = gib[jj + 512], inn = gib[jj + 1024];
  float hr = d[0] + bhh[jj], hz = d[1] + bhh[jj + 512], hn = d[2] + bhh[jj + 1024];
  float r = 1.f / (1.f + expf(-(ir + hr)));
  float z = 1.f / (1.f + expf(-(iz + hz)));
  float n = tanhf(inn + r * hn);
  float hp = hs[lb][jj];
  hnew[lb * 512 + jj] = (1.f - z) * n + z * hp;
}

// ---------------- logits GEMM (bf16 MFMA): [512,512] x [32000,512]^T + bias ----------------
// grid (125, 4): N0 = bx*256, M0 = by*128. Wave w: M=128 x N=64 tile.
__global__ __launch_bounds__(256) void k_fc(const float* __restrict__ A,
    const u16* __restrict__ Bwb, const float* __restrict__ bias, float* __restrict__ out) {
  __shared__ u16 ash[128 * 136];   // 128 rows x BK=128 (pad 8)
  int tid = threadIdx.x;
  int wave = tid >> 6;
  int lane = tid & 63;
  int quad = lane >> 4;
  int lr = lane & 15;
  int N0 = blockIdx.x * 256;
  int M0 = blockIdx.y * 128;

  f32x4 acc[8][4];
#pragma unroll
  for (int mf = 0; mf < 8; mf++)
#pragma unroll
    for (int nf = 0; nf < 4; nf++) acc[mf][nf] = (f32x4){0.f, 0.f, 0.f, 0.f};

  int arow = tid >> 1;            // 0..127
  int acol = (tid & 1) * 64;      // 0 or 64
  for (int kc = 0; kc < 512; kc += 128) {
    // stage A chunk fp32 -> bf16 LDS
#pragma unroll
    for (int j = 0; j < 16; j++) {
      float4 v = *(const float4*)(A + (size_t)(M0 + arow) * 512 + kc + acol + j * 4);
      union { u16 h[4]; uint2 u; } pk;
      pk.h[0] = f2bf(v.x); pk.h[1] = f2bf(v.y); pk.h[2] = f2bf(v.z); pk.h[3] = f2bf(v.w);
      *(uint2*)(&ash[arow * 136 + acol + j * 4]) = pk.u;
    }
    __syncthreads();
#pragma unroll
    for (int ks = 0; ks < 128; ks += 32) {
      bf16x8 af[8];
#pragma unroll
      for (int mf = 0; mf < 8; mf++)
        af[mf] = *(const bf16x8*)(&ash[(mf * 16 + lr) * 136 + ks + quad * 8]);
      bf16x8 bf[4];
#pragma unroll
      for (int nf = 0; nf < 4; nf++) {
        int n = N0 + wave * 64 + nf * 16 + lr;
        bf[nf] = *(const bf16x8*)(Bwb + (size_t)n * 512 + kc + ks + quad * 8);
      }
#pragma unroll
      for (int mf = 0; mf < 8; mf++)
#pragma unroll
        for (int nf = 0; nf < 4; nf++)
          acc[mf][nf] = __builtin_amdgcn_mfma_f32_16x16x32_bf16(af[mf], bf[nf], acc[mf][nf], 0, 0, 0);
    }
    __syncthreads();
  }

#pragma unroll
  for (int nf = 0; nf < 4; nf++) {
    int j = N0 + wave * 64 + nf * 16 + lr;
    float bv = bias[j];
#pragma unroll
    for (int mf = 0; mf < 8; mf++)
#pragma unroll
      for (int r = 0; r < 4; r++) {
        int m = M0 + mf * 16 + quad * 4 + r;   // m = t*16 + b
        int orow = (m & 15) * 32 + (m >> 4);   // out row = b*32 + t
        out[(size_t)orow * 32000 + j] = acc[mf][nf][r] + bv;
      }
  }
}

extern "C" void kernel_launch(void* const* d_in, const int* in_sizes, int n_in,
                              void* d_out, int out_size, void* d_ws, size_t ws_size,
                              hipStream_t stream) {
  const float* images  = (const float*)d_in[0];
  const int*   caps    = (const int*)d_in[1];
  const float* conv1_w = (const float*)d_in[2];
  const float* bn1_g   = (const float*)d_in[3];
  const float* bn1_b   = (const float*)d_in[4];
  const float* dw_w    = (const float*)d_in[5];
  const float* pw_w    = (const float*)d_in[6];
  const float* bn2_g   = (const float*)d_in[7];
  const float* bn2_b   = (const float*)d_in[8];
  const float* se1     = (const float*)d_in[9];
  const float* se2     = (const float*)d_in[10];
  const float* encw    = (const float*)d_in[11];
  const float* encb    = (const float*)d_in[12];
  const float* embed   = (const float*)d_in[13];
  // d_in[14]=q_w, d_in[15]=k_w are unused by the reference
  const float* vw      = (const float*)d_in[16];
  const float* wih     = (const float*)d_in[17];
  const float* whh     = (const float*)d_in[18];
  const float* bih     = (const float*)d_in[19];
  const float* bhh     = (const float*)d_in[20];
  const float* fcw     = (const float*)d_in[21];
  const float* fcb     = (const float*)d_in[22];
  float* out = (float*)d_out;

  // ---- workspace (~120 MB peak); fcwb aliases conv1out (dead after pass-1) ----
  char* ws = (char*)d_ws;
  size_t off = 0;
  auto alloc = [&](size_t bytes) {
    void* p = ws + off;
    off = (off + bytes + 255) & ~(size_t)255;
    return p;
  };
  u16*   conv1out = (u16*)alloc((size_t)51380224 * 2);        // 98 MB bf16 NHWC
  u16*   fcwb     = (u16*)conv1out;                           // 32.8 MB alias, used after pass-1
  u16*   bwb      = (u16*)alloc((size_t)131072 * 2);          // pw_w bf16
  float* partials = (float*)alloc((size_t)3136 * 1024 * 4);   // 12.8 MB
  float* p2       = (float*)alloc((size_t)64 * 1024 * 4);
  float* stats1   = (float*)alloc(512 * 4);
  float* h_all    = (float*)alloc((size_t)33 * 8192 * 4);
  float* bn1p     = (float*)alloc(512 * 4);
  float* bn2p     = (float*)alloc(1024 * 4);
  float* yb       = (float*)alloc(8192 * 4);
  float* ctxgi    = (float*)alloc((size_t)16 * 1536 * 4);
  float* gi       = (float*)alloc((size_t)32 * 16 * 1536 * 4);
  (void)ws_size; (void)in_sizes; (void)n_in; (void)out_size;

  hipMemsetAsync(stats1, 0, 512 * 4, stream);
  hipMemsetAsync(h_all, 0, 8192 * 4, stream);   // h0 = 0

  k_conv1<<<896, 256, 0, stream>>>(images, conv1_w, conv1out, stats1);
  k_bnfin<<<1, 256, 0, stream>>>(stats1, bn1_g, bn1_b, bn1p, 256, 1.f / (float)NSTAT);
  k_cvt4<<<128, 256, 0, stream>>>(pw_w, bwb, 32768);
  k_pwpass<<<3136, 256, 0, stream>>>(conv1out, bn1p, dw_w, bwb, partials, bn2p, 0);
  k_red1<<<64, 256, 0, stream>>>(partials, p2);
  k_red_bn2<<<2, 256, 0, stream>>>(p2, bn2_g, bn2_b, bn2p);
  k_pwpass<<<3136, 256, 0, stream>>>(conv1out, bn1p, dw_w, bwb, partials, bn2p, 1);
  k_red_y<<<32, 256, 0, stream>>>(partials, yb);
  k_cvt4<<<16000, 256, 0, stream>>>(fcw, fcwb, 4096000);   // aliases conv1out (now dead)
  k_se<<<16, 256, 0, stream>>>(yb, se1, se2, encw, encb, vw, wih, bih, ctxgi);
  dim3 ggi(32, 96);
  k_gi<<<ggi, 256, 0, stream>>>(caps, embed, wih, ctxgi, gi);
  for (int t = 0; t < 32; t++)
    k_gru<<<32, 256, 0, stream>>>(whh, bhh, gi, h_all, t);
  dim3 gfc(125, 4);
  k_fc<<<gfc, 256, 0, stream>>>(h_all + 8192, fcwb, fcb, out);
}